// Round 14
// baseline (324.972 us; speedup 1.0000x reference)
//
#include <hip/hip_runtime.h>
#include <hip/hip_bf16.h>
#include <hip/hip_fp16.h>

#define N_NODES 50000
#define E_EDGES 1600000
#define IN_CH 128
#define HID 32
#define HEADS 4
#define HC (HEADS * HID)         // 128
#define OUT_CH 16
#define B_GRAPHS 512
#define NEG_SLOPE 0.2f
#define CAP 96                   // per-node capacity; deg = 1+Pois(32), P(>96)~1e-18
#define NB 256                   // coarse buckets
#define BNODES 196               // nodes per bucket
#define BSUB 49                  // nodes per aggB block (4 blocks/bucket)
#define PCAP 7168                // per-bucket edge capacity (+11.6 sd)
#define ACHUNK 4096              // edges per pass-A block
#define APART 391                // ceil(E_EDGES / ACHUNK)
#define ROWS_PB 64
#define GEMM_BLOCKS 782          // ceil(50000 / 64)
#define SXS 33                   // sX row stride (floats)

__device__ __forceinline__ unsigned short f2bf(float f) {
    unsigned int u = __float_as_uint(f);
    unsigned int r = (u + 0x7FFFu + ((u >> 16) & 1u)) >> 16;   // RNE
    return (unsigned short)r;
}

__device__ __forceinline__ float lrelu_exp(float v) {
    v = v > 0.f ? v : NEG_SLOPE * v;
    return __expf(v);
}

// ---- K1: fused pass-A radix partition + slim-LDS GEMM -------------------
// LDS/block ~25 KB -> 6 blocks/CU (was 48 KB -> 3).
__global__ __launch_bounds__(256) void k_fused(const float* __restrict__ x,
                                               const float* __restrict__ W1,
                                               const float* __restrict__ att_src,
                                               const float* __restrict__ att_dst,
                                               const int* __restrict__ ei,
                                               unsigned short* __restrict__ hb,
                                               float* __restrict__ a_s,
                                               float* __restrict__ a_d,
                                               int* __restrict__ gcur,
                                               unsigned int* __restrict__ ebuf,
                                               float* __restrict__ g) {
    __shared__ float smem[6208];           // 24.8 KB: sX 64x33 | sW 32x128
    const int t = threadIdx.x;

    if (blockIdx.x < APART) {
        // ---- pass A with per-wave sub-histograms ----
        int* scnt = (int*)smem;            // [4][NB]
        int* sbase = scnt + 4 * NB;        // [4][NB]  (total 8 KB)
        const int wv = t >> 6;
        const int e0 = blockIdx.x * ACHUNK;
        int e1 = e0 + ACHUNK; if (e1 > E_EDGES) e1 = E_EDGES;
        for (int i = t; i < 4 * NB; i += 256) scnt[i] = 0;
        __syncthreads();
        const int* __restrict__ dstp = ei + E_EDGES;
        for (int e = e0 + t; e < e1; e += 256) {
            int d = dstp[e];
            atomicAdd(&scnt[wv * NB + d / BNODES], 1);
        }
        __syncthreads();
        if (t < NB) {
            int c0 = scnt[0 * NB + t], c1 = scnt[1 * NB + t];
            int c2 = scnt[2 * NB + t], c3 = scnt[3 * NB + t];
            int base = atomicAdd(&gcur[t], c0 + c1 + c2 + c3);
            sbase[0 * NB + t] = base;
            sbase[1 * NB + t] = base + c0;
            sbase[2 * NB + t] = base + c0 + c1;
            sbase[3 * NB + t] = base + c0 + c1 + c2;
            scnt[0 * NB + t] = 0; scnt[1 * NB + t] = 0;
            scnt[2 * NB + t] = 0; scnt[3 * NB + t] = 0;
        }
        __syncthreads();
        for (int e = e0 + t; e < e1; e += 256) {
            int d = dstp[e];
            int s = ei[e];
            int b = d / BNODES;
            int dl = d - b * BNODES;
            int pos = sbase[wv * NB + b] + atomicAdd(&scnt[wv * NB + b], 1);
            if (pos < PCAP)
                ebuf[(size_t)b * PCAP + pos] = ((unsigned int)dl << 16) | (unsigned int)s;
        }
        return;                            // uniform exit
    }

    // ---- GEMM part: 64 rows, 8x4 acc, k-sliced sX ----
    float* sX = smem;                      // [64][SXS] current k-slice
    float* sW = smem + 64 * SXS;           // [32][128]
    const int bid = blockIdx.x - APART;
    const int n0 = bid * ROWS_PB;

    int gt = bid * 256 + t;
    if (gt < B_GRAPHS * HC) g[gt] = 0.f;   // fused g-zero

    float acc[8][4];
#pragma unroll
    for (int j = 0; j < 8; j++)
#pragma unroll
        for (int c = 0; c < 4; c++) acc[j][c] = 0.f;

    const int tx = t & 31;    // col group: cols 4tx..4tx+3
    const int ty = t >> 5;    // row group: rows 8ty..8ty+7

    for (int kb = 0; kb < 4; kb++) {
        __syncthreads();
        // stage x k-slice [64 rows][32 k] (float4)
        for (int i = t; i < 512; i += 256) {
            int r = i >> 3, c4 = i & 7;
            int n = n0 + r;
            float4 v = (n < N_NODES)
                ? ((const float4*)x)[(size_t)n * 32 + kb * 8 + c4]
                : make_float4(0.f, 0.f, 0.f, 0.f);
            *(float4*)&sX[r * SXS + c4 * 4] = v;
        }
        // stage W k-slice [32 k][128 cols]
        for (int i = t; i < 1024; i += 256) {
            ((float4*)sW)[i] =
                ((const float4*)W1)[(size_t)(kb * 32 + (i >> 5)) * 32 + (i & 31)];
        }
        __syncthreads();
#pragma unroll
        for (int kk = 0; kk < 32; kk += 4) {
            float4 w0 = *(float4*)&sW[(kk + 0) * 128 + tx * 4];
            float4 w1 = *(float4*)&sW[(kk + 1) * 128 + tx * 4];
            float4 w2 = *(float4*)&sW[(kk + 2) * 128 + tx * 4];
            float4 w3 = *(float4*)&sW[(kk + 3) * 128 + tx * 4];
#pragma unroll
            for (int j = 0; j < 8; j++) {
                float4 xv = *(float4*)&sX[(ty * 8 + j) * SXS + kk];
                acc[j][0] += xv.x * w0.x + xv.y * w1.x + xv.z * w2.x + xv.w * w3.x;
                acc[j][1] += xv.x * w0.y + xv.y * w1.y + xv.z * w2.y + xv.w * w3.y;
                acc[j][2] += xv.x * w0.z + xv.y * w1.z + xv.z * w2.z + xv.w * w3.z;
                acc[j][3] += xv.x * w0.w + xv.y * w1.w + xv.z * w2.w + xv.w * w3.w;
            }
        }
    }

    // store h as bf16
#pragma unroll
    for (int j = 0; j < 8; j++) {
        int n = n0 + ty * 8 + j;
        if (n < N_NODES) {
            ushort4 o;
            o.x = f2bf(acc[j][0]); o.y = f2bf(acc[j][1]);
            o.z = f2bf(acc[j][2]); o.w = f2bf(acc[j][3]);
            *(ushort4*)&hb[(size_t)n * HC + tx * 4] = o;
        }
    }

    // attention scores: two 32-row halves through a [32][129] overlay
    float* sH = smem;                      // 4128 floats = 16.5 KB (fits)
    for (int half = 0; half < 2; half++) {
        __syncthreads();
        if ((ty >> 2) == half) {
            int rbase = (ty & 3) * 8;
#pragma unroll
            for (int j = 0; j < 8; j++) {
                float* row = &sH[(rbase + j) * 129 + tx * 4];
                row[0] = acc[j][0]; row[1] = acc[j][1];
                row[2] = acc[j][2]; row[3] = acc[j][3];
            }
        }
        __syncthreads();
        if (t < 64) {
            int r = t & 31;
            int n = n0 + half * 32 + r;
            const float* __restrict__ av = (t < 32) ? att_src : att_dst;
            float s0 = 0.f, s1 = 0.f, s2 = 0.f, s3 = 0.f;
#pragma unroll 4
            for (int j = 0; j < 32; j++) {
                const float* row = &sH[r * 129 + j];
                s0 += row[0]  * av[j];
                s1 += row[32] * av[32 + j];
                s2 += row[64] * av[64 + j];
                s3 += row[96] * av[96 + j];
            }
            if (n < N_NODES) {
                float* dst = (t < 32) ? a_s : a_d;
                *(float4*)(dst + (size_t)n * 4) = make_float4(s0, s1, s2, s3);
            }
        }
    }
}

// ---- K2: fused pass-B + aggregate, 4 blocks/bucket (49 nodes each) ------
// Each block scans its bucket's ebuf segment, keeps its 49-node sub-range
// in a ~16 KB LDS CSR, then 4 waves aggregate ~13 nodes each (2 ch/lane).
#define NPW 13                    // ceil(BSUB / 4)
__global__ __launch_bounds__(256) void k_aggB(const unsigned int* __restrict__ ebuf,
                                              const int* __restrict__ gcur,
                                              const float* __restrict__ a_s,
                                              const float* __restrict__ a_d,
                                              const unsigned short* __restrict__ hb,
                                              const float* __restrict__ b1,
                                              const int* __restrict__ batch,
                                              float* __restrict__ g) {
    __shared__ unsigned short sbuf[BSUB * CAP];     // 9408 B
    __shared__ int scnt[BSUB];                      //  196 B
    __shared__ float sWt[4][4][97];                 // 6208 B  (~15.8 KB total)
    const int t = threadIdx.x;
    const int bucket = blockIdx.x >> 2;
    const int sub = blockIdx.x & 3;
    const int l0 = sub * BSUB;             // local node range [l0, l0+49)
    const int dbase = bucket * BNODES + l0;

    // phase 1: self-loop seed + LDS scatter of in-range edges
    for (int i = t; i < BSUB; i += 256) {
        int d = dbase + i;
        scnt[i] = (d < N_NODES) ? 1 : 0;
        sbuf[i * CAP] = (unsigned short)d;
    }
    __syncthreads();
    int m = gcur[bucket]; if (m > PCAP) m = PCAP;
    const unsigned int* __restrict__ seg = ebuf + (size_t)bucket * PCAP;
    for (int i = t; i < m; i += 256) {
        unsigned int p = seg[i];
        int dl = (int)(p >> 16) - l0;
        if ((unsigned)dl < BSUB) {
            int c = atomicAdd(&scnt[dl], 1);
            if (c < CAP) sbuf[dl * CAP + c] = (unsigned short)(p & 0xFFFFu);
        }
    }
    __syncthreads();

    // phase 2: wave wv aggregates local nodes [wv*NPW, min(+NPW, BSUB))
    const int wv = t >> 6;
    const int l = t & 63;
    const int head = l >> 4;
    const int c0 = 2 * l;
    int nl0 = wv * NPW;
    int nl1 = nl0 + NPW; if (nl1 > BSUB) nl1 = BSUB;
    int gn0 = dbase + nl0;
    if (gn0 >= N_NODES || nl0 >= BSUB) return;
    int gn1 = dbase + nl1; if (gn1 > N_NODES) gn1 = N_NODES;
    const float2 bias = *(const float2*)(b1 + c0);
    float pool0 = 0.f, pool1 = 0.f;
    int cur = batch[gn0];
    for (int n = gn0; n < gn1; n++) {
        int bb = batch[n];
        if (bb != cur) {                   // wave-uniform branch
            atomicAdd(&g[(size_t)cur * HC + c0], pool0);
            atomicAdd(&g[(size_t)cur * HC + c0 + 1], pool1);
            pool0 = pool1 = 0.f;
            cur = bb;
        }
        int nl = n - dbase;
        int c = scnt[nl]; if (c > CAP) c = CAP;
        float4 ad = *(const float4*)(a_d + (size_t)n * 4);
        const unsigned short* __restrict__ srow = &sbuf[nl * CAP];
        for (int i = l; i < c; i += 64) {  // weight fill (this wave only)
            int s = srow[i];
            float4 as = *(const float4*)(a_s + (size_t)s * 4);
            sWt[wv][0][i] = lrelu_exp(as.x + ad.x);
            sWt[wv][1][i] = lrelu_exp(as.y + ad.y);
            sWt[wv][2][i] = lrelu_exp(as.z + ad.z);
            sWt[wv][3][i] = lrelu_exp(as.w + ad.w);
        }
        __asm__ volatile("" ::: "memory"); // wave-coherent LDS
        const float* __restrict__ wrow = &sWt[wv][head][0];
        float acc0 = 0.f, acc1 = 0.f, dsum = 0.f;
        int i = 0;
        for (; i + 4 <= c; i += 4) {
            int s0 = srow[i], s1 = srow[i + 1], s2 = srow[i + 2], s3 = srow[i + 3];
            float w0 = wrow[i], w1 = wrow[i + 1], w2 = wrow[i + 2], w3 = wrow[i + 3];
            unsigned int u0 = *(const unsigned int*)(hb + (size_t)s0 * HC + c0);
            unsigned int u1 = *(const unsigned int*)(hb + (size_t)s1 * HC + c0);
            unsigned int u2 = *(const unsigned int*)(hb + (size_t)s2 * HC + c0);
            unsigned int u3 = *(const unsigned int*)(hb + (size_t)s3 * HC + c0);
            dsum += (w0 + w1) + (w2 + w3);
            acc0 += w0 * __uint_as_float(u0 << 16) + w1 * __uint_as_float(u1 << 16)
                  + w2 * __uint_as_float(u2 << 16) + w3 * __uint_as_float(u3 << 16);
            acc1 += w0 * __uint_as_float(u0 & 0xFFFF0000u)
                  + w1 * __uint_as_float(u1 & 0xFFFF0000u)
                  + w2 * __uint_as_float(u2 & 0xFFFF0000u)
                  + w3 * __uint_as_float(u3 & 0xFFFF0000u);
        }
        for (; i < c; i++) {
            int s0 = srow[i];
            float w0 = wrow[i];
            unsigned int u0 = *(const unsigned int*)(hb + (size_t)s0 * HC + c0);
            dsum += w0;
            acc0 += w0 * __uint_as_float(u0 << 16);
            acc1 += w0 * __uint_as_float(u0 & 0xFFFF0000u);
        }
        __asm__ volatile("" ::: "memory");
        float inv = 1.f / (dsum + 1e-16f);
        float v0 = acc0 * inv + bias.x; v0 = v0 > 0.f ? v0 : (__expf(v0) - 1.f);
        float v1 = acc1 * inv + bias.y; v1 = v1 > 0.f ? v1 : (__expf(v1) - 1.f);
        pool0 += v0;
        pool1 += v1;
    }
    atomicAdd(&g[(size_t)cur * HC + c0], pool0);
    atomicAdd(&g[(size_t)cur * HC + c0 + 1], pool1);
}

// ---------------- K3: tiny 2-layer MLP on pooled graphs ------------------
__global__ __launch_bounds__(64) void k_mlp(const float* __restrict__ g,
                                            const float* __restrict__ w1,
                                            const float* __restrict__ bb1,
                                            const float* __restrict__ w2,
                                            const float* __restrict__ bb2,
                                            float* __restrict__ out) {
    __shared__ float sg[HC];
    __shared__ float st[HID];
    int b = blockIdx.x;
    int t = threadIdx.x;   // 64
    sg[t]      = g[(size_t)b * HC + t];
    sg[t + 64] = g[(size_t)b * HC + 64 + t];
    __syncthreads();
    if (t < HID) {
        float acc = bb1[t];
#pragma unroll 8
        for (int k = 0; k < HC; k++) acc += sg[k] * w1[(size_t)k * HID + t];
        st[t] = acc;
    }
    __syncthreads();
    if (t < OUT_CH) {
        float acc = bb2[t];
#pragma unroll
        for (int k = 0; k < HID; k++) acc += st[k] * w2[(size_t)k * OUT_CH + t];
        out[(size_t)b * OUT_CH + t] = acc;
    }
}

extern "C" void kernel_launch(void* const* d_in, const int* in_sizes, int n_in,
                              void* d_out, int out_size, void* d_ws, size_t ws_size,
                              hipStream_t stream) {
    const float* x       = (const float*)d_in[0];
    const int*   ei      = (const int*)d_in[1];
    const int*   batch   = (const int*)d_in[2];
    const float* W1      = (const float*)d_in[3];
    const float* att_src = (const float*)d_in[4];
    const float* att_dst = (const float*)d_in[5];
    const float* b1      = (const float*)d_in[6];
    const float* lin1_w  = (const float*)d_in[7];
    const float* lin1_b  = (const float*)d_in[8];
    const float* lin2_w  = (const float*)d_in[9];
    const float* lin2_b  = (const float*)d_in[10];
    float* out = (float*)d_out;

    float* ws = (float*)d_ws;
    // layout (float-offsets into ws):
    unsigned short* hb   = (unsigned short*)ws;    // N*128 bf16 -> 3,200,000 floats
    float*  a_s      = ws + 3200000;               //   200,000
    float*  a_d      = ws + 3400000;               //   200,000
    unsigned int* ebuf = (unsigned int*)(ws + 3600000);     // NB*PCAP = 1,835,008
    int*    gcur     = (int*)(ws + 5435008);       //       256
    float*  g        = ws + 5436000;               //    65,536
    // total ~5.5M floats = 22 MB

    hipMemsetAsync(gcur, 0, NB * sizeof(int), stream);

    k_fused<<<APART + GEMM_BLOCKS, 256, 0, stream>>>(
        x, W1, att_src, att_dst, ei, hb, a_s, a_d, gcur, ebuf, g);
    k_aggB<<<NB * 4, 256, 0, stream>>>(ebuf, gcur, a_s, a_d, hb, b1, batch, g);
    k_mlp<<<B_GRAPHS, 64, 0, stream>>>(g, lin1_w, lin1_b, lin2_w, lin2_b, out);
}

// Round 15
// 215.925 us; speedup vs baseline: 1.5050x; 1.5050x over previous
//
#include <hip/hip_runtime.h>
#include <hip/hip_bf16.h>
#include <hip/hip_fp16.h>

#define N_NODES 50000
#define E_EDGES 1600000
#define IN_CH 128
#define HID 32
#define HEADS 4
#define HC (HEADS * HID)         // 128
#define OUT_CH 16
#define B_GRAPHS 512
#define NEG_SLOPE 0.2f
#define CAP 96                   // per-node capacity; deg = 1+Pois(32), P(>96)~1e-18
#define NB 256                   // coarse buckets
#define BNODES 196               // nodes per bucket
#define PCAP 7168                // per-bucket edge capacity (+11.6 sd)
#define ACHUNK 4096              // edges per pass-A block
#define APART 391                // ceil(E_EDGES / ACHUNK)
#define ROWS_PB 64
#define GEMM_BLOCKS 782          // ceil(50000 / 64)
#define TOT_BLOCKS 1173          // APART + GEMM_BLOCKS, interleaved 1:2

__device__ __forceinline__ unsigned short f2bf(float f) {
    unsigned int u = __float_as_uint(f);
    unsigned int r = (u + 0x7FFFu + ((u >> 16) & 1u)) >> 16;   // RNE
    return (unsigned short)r;
}

__device__ __forceinline__ float lrelu_exp(float v) {
    v = v > 0.f ? v : NEG_SLOPE * v;
    return __expf(v);
}

// ---- K1: fused pass-A + GEMM, INTERLEAVED block mapping ------------------
// blockIdx%3==0 -> partA chunk blockIdx/3; else GEMM tile. Memory-bound
// partA waves co-schedule with VALU/LDS-bound GEMM waves on the same CUs.
// GEMM body is R12-exact (120 VGPR — do not restructure; 8x8 tile spills
// at 256 VGPR [R11], k-sliced staging hits 140 VGPR = half occupancy [R14]).
__global__ __launch_bounds__(256) void k_fused(const float* __restrict__ x,
                                               const float* __restrict__ W1,
                                               const float* __restrict__ att_src,
                                               const float* __restrict__ att_dst,
                                               const int* __restrict__ ei,
                                               unsigned short* __restrict__ hb,
                                               float* __restrict__ a_s,
                                               float* __restrict__ a_d,
                                               int* __restrict__ gcur,
                                               unsigned int* __restrict__ ebuf,
                                               float* __restrict__ g) {
    __shared__ float smem[12288];          // 48 KB
    const int t = threadIdx.x;
    const int bI = blockIdx.x;

    if (bI % 3 == 0) {
        // ---- pass A with per-wave sub-histograms ----
        const int ablk = bI / 3;           // 0..390
        int* scnt = (int*)smem;            // [4][NB]
        int* sbase = scnt + 4 * NB;        // [4][NB]
        const int wv = t >> 6;
        const int e0 = ablk * ACHUNK;
        int e1 = e0 + ACHUNK; if (e1 > E_EDGES) e1 = E_EDGES;
        for (int i = t; i < 4 * NB; i += 256) scnt[i] = 0;
        __syncthreads();
        const int* __restrict__ dstp = ei + E_EDGES;
        for (int e = e0 + t; e < e1; e += 256) {
            int d = dstp[e];
            atomicAdd(&scnt[wv * NB + d / BNODES], 1);
        }
        __syncthreads();
        if (t < NB) {
            int c0 = scnt[0 * NB + t], c1 = scnt[1 * NB + t];
            int c2 = scnt[2 * NB + t], c3 = scnt[3 * NB + t];
            int base = atomicAdd(&gcur[t], c0 + c1 + c2 + c3);
            sbase[0 * NB + t] = base;
            sbase[1 * NB + t] = base + c0;
            sbase[2 * NB + t] = base + c0 + c1;
            sbase[3 * NB + t] = base + c0 + c1 + c2;
            scnt[0 * NB + t] = 0; scnt[1 * NB + t] = 0;
            scnt[2 * NB + t] = 0; scnt[3 * NB + t] = 0;
        }
        __syncthreads();
        for (int e = e0 + t; e < e1; e += 256) {
            int d = dstp[e];
            int s = ei[e];
            int b = d / BNODES;
            int dl = d - b * BNODES;
            int pos = sbase[wv * NB + b] + atomicAdd(&scnt[wv * NB + b], 1);
            if (pos < PCAP)
                ebuf[(size_t)b * PCAP + pos] = ((unsigned int)dl << 16) | (unsigned int)s;
        }
        return;                            // uniform exit
    }

    // ---- GEMM part (R12-exact: 64 rows, 8x4 acc, 120 VGPR) ----
    float* sX = smem;                      // [64][128]
    float* sW = smem + 8192;               // [32][128]
    const int bid = bI - bI / 3 - 1;       // 0..781
    const int n0 = bid * ROWS_PB;

    int gt = bid * 256 + t;
    if (gt < B_GRAPHS * HC) g[gt] = 0.f;   // fused g-zero

    for (int i = t; i < ROWS_PB * 32; i += 256) {
        int r = i >> 5, c4 = i & 31;
        int n = n0 + r;
        float4 v = (n < N_NODES) ? ((const float4*)x)[(size_t)n * 32 + c4]
                                 : make_float4(0.f, 0.f, 0.f, 0.f);
        ((float4*)sX)[i] = v;
    }

    float acc[8][4];
#pragma unroll
    for (int j = 0; j < 8; j++)
#pragma unroll
        for (int c = 0; c < 4; c++) acc[j][c] = 0.f;

    const int tx = t & 31;    // col group: cols 4tx..4tx+3
    const int ty = t >> 5;    // row group: rows 8ty..8ty+7

    for (int kb = 0; kb < 4; kb++) {
        __syncthreads();
        for (int i = t; i < 32 * 32; i += 256) {
            ((float4*)sW)[i] =
                ((const float4*)W1)[(size_t)(kb * 32 + (i >> 5)) * 32 + (i & 31)];
        }
        __syncthreads();
#pragma unroll
        for (int kk = 0; kk < 32; kk += 4) {
            float4 w0 = *(float4*)&sW[(kk + 0) * 128 + tx * 4];
            float4 w1 = *(float4*)&sW[(kk + 1) * 128 + tx * 4];
            float4 w2 = *(float4*)&sW[(kk + 2) * 128 + tx * 4];
            float4 w3 = *(float4*)&sW[(kk + 3) * 128 + tx * 4];
#pragma unroll
            for (int j = 0; j < 8; j++) {
                float4 xv = *(float4*)&sX[(ty * 8 + j) * 128 + kb * 32 + kk];
                acc[j][0] += xv.x * w0.x + xv.y * w1.x + xv.z * w2.x + xv.w * w3.x;
                acc[j][1] += xv.x * w0.y + xv.y * w1.y + xv.z * w2.y + xv.w * w3.y;
                acc[j][2] += xv.x * w0.z + xv.y * w1.z + xv.z * w2.z + xv.w * w3.z;
                acc[j][3] += xv.x * w0.w + xv.y * w1.w + xv.z * w2.w + xv.w * w3.w;
            }
        }
    }

#pragma unroll
    for (int j = 0; j < 8; j++) {
        int n = n0 + ty * 8 + j;
        if (n < N_NODES) {
            ushort4 o;
            o.x = f2bf(acc[j][0]); o.y = f2bf(acc[j][1]);
            o.z = f2bf(acc[j][2]); o.w = f2bf(acc[j][3]);
            *(ushort4*)&hb[(size_t)n * HC + tx * 4] = o;
        }
    }

    // attention scores from the fp32 tile (restash with pad-129)
    __syncthreads();
    float* sH = smem;                      // [64][129]
#pragma unroll
    for (int j = 0; j < 8; j++) {
        float* row = &sH[(ty * 8 + j) * 129 + tx * 4];
        row[0] = acc[j][0]; row[1] = acc[j][1];
        row[2] = acc[j][2]; row[3] = acc[j][3];
    }
    __syncthreads();
    if (t < 128) {
        int r = t & 63;
        int n = n0 + r;
        const float* __restrict__ av = (t < 64) ? att_src : att_dst;
        float s0 = 0.f, s1 = 0.f, s2 = 0.f, s3 = 0.f;
#pragma unroll 4
        for (int j = 0; j < 32; j++) {
            const float* row = &sH[r * 129 + j];
            s0 += row[0]  * av[j];
            s1 += row[32] * av[32 + j];
            s2 += row[64] * av[64 + j];
            s3 += row[96] * av[96 + j];
        }
        if (n < N_NODES) {
            float* dst = (t < 64) ? a_s : a_d;
            *(float4*)(dst + (size_t)n * 4) = make_float4(s0, s1, s2, s3);
        }
    }
}

// ---- K2: fused pass-B + aggregate + pool (one 1024-thr block / bucket) --
// 8-edge unrolled gather: 8 outstanding loads/wave x 16 waves/CU.
#define NPW 13                    // ceil(BNODES / 16)
__global__ __launch_bounds__(1024) void k_aggB(const unsigned int* __restrict__ ebuf,
                                               const int* __restrict__ gcur,
                                               const float* __restrict__ a_s,
                                               const float* __restrict__ a_d,
                                               const unsigned short* __restrict__ hb,
                                               const float* __restrict__ b1,
                                               const int* __restrict__ batch,
                                               float* __restrict__ g) {
    __shared__ unsigned short sbuf[BNODES * CAP];   // 37632 B
    __shared__ int scnt[BNODES];                    //   784 B
    __shared__ float sWt[16][4][97];                // 24832 B  (63 KB total)
    const int t = threadIdx.x;
    const int b = blockIdx.x;
    const int dbase = b * BNODES;

    // phase 1: self-loop seed + LDS scatter of this bucket's edges
    for (int i = t; i < BNODES; i += 1024) {
        int d = dbase + i;
        scnt[i] = (d < N_NODES) ? 1 : 0;
        sbuf[i * CAP] = (unsigned short)d;
    }
    __syncthreads();
    int m = gcur[b]; if (m > PCAP) m = PCAP;
    for (int i = t; i < m; i += 1024) {
        unsigned int p = ebuf[(size_t)b * PCAP + i];
        int dl = p >> 16;
        int s = p & 0xFFFFu;
        int c = atomicAdd(&scnt[dl], 1);
        if (c < CAP) sbuf[dl * CAP + c] = (unsigned short)s;
    }
    __syncthreads();

    // phase 2: wave wv aggregates nodes [wv*NPW, min((wv+1)*NPW, BNODES))
    const int wv = t >> 6;
    const int l = t & 63;
    const int head = l >> 4;
    const int c0 = 2 * l;
    int nl0 = wv * NPW;
    int nl1 = nl0 + NPW; if (nl1 > BNODES) nl1 = BNODES;
    int gn0 = dbase + nl0;
    if (gn0 >= N_NODES) return;
    int gn1 = dbase + nl1; if (gn1 > N_NODES) gn1 = N_NODES;
    const float2 bias = *(const float2*)(b1 + c0);
    float pool0 = 0.f, pool1 = 0.f;
    int cur = batch[gn0];
    for (int n = gn0; n < gn1; n++) {
        int bb = batch[n];
        if (bb != cur) {                   // wave-uniform branch
            atomicAdd(&g[(size_t)cur * HC + c0], pool0);
            atomicAdd(&g[(size_t)cur * HC + c0 + 1], pool1);
            pool0 = pool1 = 0.f;
            cur = bb;
        }
        int nl = n - dbase;
        int c = scnt[nl]; if (c > CAP) c = CAP;
        float4 ad = *(const float4*)(a_d + (size_t)n * 4);
        const unsigned short* __restrict__ srow = &sbuf[nl * CAP];
        for (int i = l; i < c; i += 64) {  // weight fill (this wave only)
            int s = srow[i];
            float4 as = *(const float4*)(a_s + (size_t)s * 4);
            sWt[wv][0][i] = lrelu_exp(as.x + ad.x);
            sWt[wv][1][i] = lrelu_exp(as.y + ad.y);
            sWt[wv][2][i] = lrelu_exp(as.z + ad.z);
            sWt[wv][3][i] = lrelu_exp(as.w + ad.w);
        }
        __asm__ volatile("" ::: "memory"); // wave-coherent LDS
        const float* __restrict__ wrow = &sWt[wv][head][0];
        float acc0 = 0.f, acc1 = 0.f, dsum = 0.f;
        int i = 0;
        for (; i + 8 <= c; i += 8) {       // 8-edge interleave for MLP
            unsigned int u[8];
            float w[8];
#pragma unroll
            for (int q = 0; q < 8; q++) {
                int sq = srow[i + q];
                w[q] = wrow[i + q];
                u[q] = *(const unsigned int*)(hb + (size_t)sq * HC + c0);
            }
#pragma unroll
            for (int q = 0; q < 8; q++) {
                dsum += w[q];
                acc0 += w[q] * __uint_as_float(u[q] << 16);
                acc1 += w[q] * __uint_as_float(u[q] & 0xFFFF0000u);
            }
        }
        for (; i < c; i++) {
            int s0 = srow[i];
            float w0 = wrow[i];
            unsigned int u0 = *(const unsigned int*)(hb + (size_t)s0 * HC + c0);
            dsum += w0;
            acc0 += w0 * __uint_as_float(u0 << 16);
            acc1 += w0 * __uint_as_float(u0 & 0xFFFF0000u);
        }
        __asm__ volatile("" ::: "memory");
        float inv = 1.f / (dsum + 1e-16f);
        float v0 = acc0 * inv + bias.x; v0 = v0 > 0.f ? v0 : (__expf(v0) - 1.f);
        float v1 = acc1 * inv + bias.y; v1 = v1 > 0.f ? v1 : (__expf(v1) - 1.f);
        pool0 += v0;
        pool1 += v1;
    }
    atomicAdd(&g[(size_t)cur * HC + c0], pool0);
    atomicAdd(&g[(size_t)cur * HC + c0 + 1], pool1);
}

// ---------------- K3: tiny 2-layer MLP on pooled graphs ------------------
__global__ __launch_bounds__(64) void k_mlp(const float* __restrict__ g,
                                            const float* __restrict__ w1,
                                            const float* __restrict__ bb1,
                                            const float* __restrict__ w2,
                                            const float* __restrict__ bb2,
                                            float* __restrict__ out) {
    __shared__ float sg[HC];
    __shared__ float st[HID];
    int b = blockIdx.x;
    int t = threadIdx.x;   // 64
    sg[t]      = g[(size_t)b * HC + t];
    sg[t + 64] = g[(size_t)b * HC + 64 + t];
    __syncthreads();
    if (t < HID) {
        float acc = bb1[t];
#pragma unroll 8
        for (int k = 0; k < HC; k++) acc += sg[k] * w1[(size_t)k * HID + t];
        st[t] = acc;
    }
    __syncthreads();
    if (t < OUT_CH) {
        float acc = bb2[t];
#pragma unroll
        for (int k = 0; k < HID; k++) acc += st[k] * w2[(size_t)k * OUT_CH + t];
        out[(size_t)b * OUT_CH + t] = acc;
    }
}

extern "C" void kernel_launch(void* const* d_in, const int* in_sizes, int n_in,
                              void* d_out, int out_size, void* d_ws, size_t ws_size,
                              hipStream_t stream) {
    const float* x       = (const float*)d_in[0];
    const int*   ei      = (const int*)d_in[1];
    const int*   batch   = (const int*)d_in[2];
    const float* W1      = (const float*)d_in[3];
    const float* att_src = (const float*)d_in[4];
    const float* att_dst = (const float*)d_in[5];
    const float* b1      = (const float*)d_in[6];
    const float* lin1_w  = (const float*)d_in[7];
    const float* lin1_b  = (const float*)d_in[8];
    const float* lin2_w  = (const float*)d_in[9];
    const float* lin2_b  = (const float*)d_in[10];
    float* out = (float*)d_out;

    float* ws = (float*)d_ws;
    // layout (float-offsets into ws):
    unsigned short* hb   = (unsigned short*)ws;    // N*128 bf16 -> 3,200,000 floats
    float*  a_s      = ws + 3200000;               //   200,000
    float*  a_d      = ws + 3400000;               //   200,000
    unsigned int* ebuf = (unsigned int*)(ws + 3600000);     // NB*PCAP = 1,835,008
    int*    gcur     = (int*)(ws + 5435008);       //       256
    float*  g        = ws + 5436000;               //    65,536
    // total ~5.5M floats = 22 MB

    hipMemsetAsync(gcur, 0, NB * sizeof(int), stream);

    k_fused<<<TOT_BLOCKS, 256, 0, stream>>>(
        x, W1, att_src, att_dst, ei, hb, a_s, a_d, gcur, ebuf, g);
    k_aggB<<<NB, 1024, 0, stream>>>(ebuf, gcur, a_s, a_d, hb, b1, batch, g);
    k_mlp<<<B_GRAPHS, 64, 0, stream>>>(g, lin1_w, lin1_b, lin2_w, lin2_b, out);
}